// Round 2
// baseline (478.236 us; speedup 1.0000x reference)
//
#include <hip/hip_runtime.h>
#include <hip/hip_bf16.h>
#include <math.h>

#define NEG_SLOPE 0.2f

typedef __bf16 bf16x8 __attribute__((ext_vector_type(8)));
typedef float  f32x4  __attribute__((ext_vector_type(4)));

// ---------------- K0: split W [256][32] fp32 into bf16 hi/lo fragment order --
// layout: frag = kt*2+nt (kt in [0,8), nt in [0,2)); element (frag*64+lane)*8+j
// B[k][n] with n = nt*16 + (lane&15), k = kt*32 + (lane>>4)*8 + j
__global__ void pack_w(const float* __restrict__ W,
                       __bf16* __restrict__ Whi, __bf16* __restrict__ Wlo) {
    int idx = blockIdx.x * blockDim.x + threadIdx.x;
    if (idx >= 8192) return;
    int j = idx & 7, lane = (idx >> 3) & 63, nt = (idx >> 9) & 1, kt = idx >> 10;
    int q = lane >> 4, c = lane & 15;
    int k = kt * 32 + q * 8 + j;
    int n = nt * 16 + c;
    float w = W[k * 32 + n];
    __bf16 hi = (__bf16)w;
    float rem = w - (float)hi;
    Whi[idx] = hi;
    Wlo[idx] = (__bf16)rem;
}

// ---------------- K1: h = feat @ W via split-bf16 MFMA + fused el/er ---------
__global__ __launch_bounds__(256) void gemm_h(const float* __restrict__ feat,
                                              const __bf16* __restrict__ Whi,
                                              const __bf16* __restrict__ Wlo,
                                              const float* __restrict__ attn_l,
                                              const float* __restrict__ attn_r,
                                              float* __restrict__ h,
                                              float* __restrict__ el,
                                              float* __restrict__ er,
                                              int N, int Ntiles) {
    int wid  = (int)((blockIdx.x * blockDim.x + threadIdx.x) >> 6);
    int lane = threadIdx.x & 63;
    if (wid >= Ntiles) return;

    const bf16x8* Bh = (const bf16x8*)Whi;
    const bf16x8* Bl = (const bf16x8*)Wlo;

    int c = lane & 15, q = lane >> 4;
    int row = wid * 16 + c;
    if (row >= N) row = N - 1;  // defensive clamp
    const float* A = feat + (size_t)row * 256 + q * 8;

    f32x4 acc0 = {0.f, 0.f, 0.f, 0.f};
    f32x4 acc1 = {0.f, 0.f, 0.f, 0.f};
#pragma unroll
    for (int kt = 0; kt < 8; kt++) {
        f32x4 a0 = *(const f32x4*)(A + kt * 32);
        f32x4 a1 = *(const f32x4*)(A + kt * 32 + 4);
        bf16x8 ah, al;
#pragma unroll
        for (int j = 0; j < 4; j++) {
            __bf16 h0 = (__bf16)a0[j];
            __bf16 h1 = (__bf16)a1[j];
            ah[j]     = h0;
            ah[j + 4] = h1;
            al[j]     = (__bf16)(a0[j] - (float)h0);
            al[j + 4] = (__bf16)(a1[j] - (float)h1);
        }
        bf16x8 bh0 = Bh[(kt * 2 + 0) * 64 + lane];
        bf16x8 bh1 = Bh[(kt * 2 + 1) * 64 + lane];
        bf16x8 bl0 = Bl[(kt * 2 + 0) * 64 + lane];
        bf16x8 bl1 = Bl[(kt * 2 + 1) * 64 + lane];
        acc0 = __builtin_amdgcn_mfma_f32_16x16x32_bf16(ah, bh0, acc0, 0, 0, 0);
        acc0 = __builtin_amdgcn_mfma_f32_16x16x32_bf16(al, bh0, acc0, 0, 0, 0);
        acc0 = __builtin_amdgcn_mfma_f32_16x16x32_bf16(ah, bl0, acc0, 0, 0, 0);
        acc1 = __builtin_amdgcn_mfma_f32_16x16x32_bf16(ah, bh1, acc1, 0, 0, 0);
        acc1 = __builtin_amdgcn_mfma_f32_16x16x32_bf16(al, bh1, acc1, 0, 0, 0);
        acc1 = __builtin_amdgcn_mfma_f32_16x16x32_bf16(ah, bl1, acc1, 0, 0, 0);
    }

    // epilogue: store h (C/D layout: col=lane&15, row=(lane>>4)*4+reg) + el/er
    float alc  = attn_l[c],      arc  = attn_r[c];
    float alc2 = attn_l[c + 16], arc2 = attn_r[c + 16];
#pragma unroll
    for (int r = 0; r < 4; r++) {
        int m = wid * 16 + q * 4 + r;
        if (m < N) {
            h[(size_t)m * 32 + c]      = acc0[r];
            h[(size_t)m * 32 + 16 + c] = acc1[r];
        }
        float pl = acc0[r] * alc + acc1[r] * alc2;
        float pr = acc0[r] * arc + acc1[r] * arc2;
#pragma unroll
        for (int off = 8; off >= 1; off >>= 1) {
            pl += __shfl_xor(pl, off);
            pr += __shfl_xor(pr, off);
        }
        if (c == 0 && m < N) { el[m] = pl; er[m] = pr; }
    }
}

// ---------------- K3: in-degree count ----------------------------------------
__global__ void count_deg(const int* __restrict__ dst, int* __restrict__ counts, int E) {
    int i = blockIdx.x * blockDim.x + threadIdx.x;
    if (i < E) atomicAdd(&counts[dst[i]], 1);
}

// ---------------- K4a: per-block sums of counts ------------------------------
__global__ __launch_bounds__(256) void block_reduce(const int* __restrict__ counts,
                                                    int* __restrict__ bsum, int N) {
    int i = blockIdx.x * 256 + threadIdx.x;
    int v = (i < N) ? counts[i] : 0;
#pragma unroll
    for (int off = 32; off >= 1; off >>= 1) v += __shfl_xor(v, off);
    __shared__ int s[4];
    if ((threadIdx.x & 63) == 0) s[threadIdx.x >> 6] = v;
    __syncthreads();
    if (threadIdx.x == 0) bsum[blockIdx.x] = s[0] + s[1] + s[2] + s[3];
}

// ---------------- K4b: scan block sums (NB <= 512), exclusive in place -------
__global__ __launch_bounds__(512) void scan_bsum(int* __restrict__ bsum, int NB,
                                                 int* __restrict__ offsets, int N) {
    __shared__ int s[512];
    int t = threadIdx.x;
    int v = (t < NB) ? bsum[t] : 0;
    s[t] = v;
    __syncthreads();
#pragma unroll
    for (int off = 1; off < 512; off <<= 1) {
        int x = (t >= off) ? s[t - off] : 0;
        __syncthreads();
        s[t] += x;
        __syncthreads();
    }
    if (t < NB) bsum[t] = (t == 0) ? 0 : s[t - 1];
    if (t == 0) offsets[N] = s[NB - 1];  // total == E
}

// ---------------- K4c: final exclusive scan -> offsets + cursor --------------
__global__ __launch_bounds__(256) void scan_final(const int* __restrict__ counts,
                                                  const int* __restrict__ bsum,
                                                  int* __restrict__ offsets,
                                                  int* __restrict__ cursor, int N) {
    __shared__ int s[256];
    int i = blockIdx.x * 256 + threadIdx.x;
    int t = threadIdx.x;
    int v = (i < N) ? counts[i] : 0;
    s[t] = v;
    __syncthreads();
#pragma unroll
    for (int off = 1; off < 256; off <<= 1) {
        int x = (t >= off) ? s[t - off] : 0;
        __syncthreads();
        s[t] += x;
        __syncthreads();
    }
    int excl = ((t == 0) ? 0 : s[t - 1]) + bsum[blockIdx.x];
    if (i < N) { offsets[i] = excl; cursor[i] = excl; }
}

// ---------------- K5: scatter edges into CSR ---------------------------------
__global__ void fill_csr(const int* __restrict__ src, const int* __restrict__ dst,
                         int* __restrict__ cursor, int* __restrict__ csr_src, int E) {
    int i = blockIdx.x * blockDim.x + threadIdx.x;
    if (i < E) {
        int p = atomicAdd(&cursor[dst[i]], 1);
        csr_src[p] = src[i];
    }
}

// ---------------- K6: per-dst softmax + weighted aggregation -----------------
__global__ __launch_bounds__(256) void aggregate(const int* __restrict__ offsets,
                                                 const int* __restrict__ csr_src,
                                                 const float* __restrict__ el,
                                                 const float* __restrict__ er,
                                                 const float* __restrict__ h,
                                                 const float* __restrict__ bias,
                                                 float* __restrict__ out, int N) {
    int w = (int)((blockIdx.x * blockDim.x + threadIdx.x) >> 6);
    int lane = threadIdx.x & 63;
    if (w >= N) return;

    int start = offsets[w], end = offsets[w + 1];
    int f = lane & 31;
    float bf = bias[f];

    if (start == end) {  // isolated node: rst = 0 (+ bias)
        if (lane < 32) out[(size_t)w * 32 + f] = bf;
        return;
    }

    float erv = er[w];

    // pass A: max score
    float mx = -INFINITY;
    for (int j = start + lane; j < end; j += 64) {
        float e = el[csr_src[j]] + erv;
        e = (e > 0.f) ? e : NEG_SLOPE * e;
        mx = fmaxf(mx, e);
    }
#pragma unroll
    for (int off = 32; off >= 1; off >>= 1) mx = fmaxf(mx, __shfl_xor(mx, off));

    // pass B: denom
    float sm = 0.f;
    for (int j = start + lane; j < end; j += 64) {
        float e = el[csr_src[j]] + erv;
        e = (e > 0.f) ? e : NEG_SLOPE * e;
        sm += __expf(e - mx);
    }
#pragma unroll
    for (int off = 32; off >= 1; off >>= 1) sm += __shfl_xor(sm, off);

    // pass C: weighted aggregation, 2 edges/iter (32 feature lanes each)
    float acc = 0.f;
    int half = lane >> 5;
    for (int j = start + half; j < end; j += 2) {
        int s = csr_src[j];
        float e = el[s] + erv;
        e = (e > 0.f) ? e : NEG_SLOPE * e;
        float wgt = __expf(e - mx);
        acc += wgt * h[(size_t)s * 32 + f];
    }
    acc += __shfl_xor(acc, 32);

    if (lane < 32) out[(size_t)w * 32 + f] = acc / sm + bf;
}

// ---------------- host launch -----------------------------------------------
static inline size_t align256(size_t x) { return (x + 255) & ~(size_t)255; }

extern "C" void kernel_launch(void* const* d_in, const int* in_sizes, int n_in,
                              void* d_out, int out_size, void* d_ws, size_t ws_size,
                              hipStream_t stream) {
    const float* feat   = (const float*)d_in[0];
    const float* W      = (const float*)d_in[1];
    const float* attn_l = (const float*)d_in[2];
    const float* attn_r = (const float*)d_in[3];
    const float* bias   = (const float*)d_in[4];
    const int* src = (const int*)d_in[5];
    const int* dst = (const int*)d_in[6];
    float* out = (float*)d_out;

    const int IN = 256;
    int N = in_sizes[0] / IN;   // 100000
    int E = in_sizes[5];        // 1600000
    (void)n_in; (void)out_size; (void)ws_size;

    char* p = (char*)d_ws;
    float* h       = (float*)p; p += align256((size_t)N * 32 * 4);
    float* el      = (float*)p; p += align256((size_t)N * 4);
    float* er      = (float*)p; p += align256((size_t)N * 4);
    int*   counts  = (int*)p;   p += align256((size_t)N * 4);
    int*   offsets = (int*)p;   p += align256((size_t)(N + 1) * 4);
    int*   cursor  = (int*)p;   p += align256((size_t)N * 4);
    int*   bsum    = (int*)p;   p += align256((size_t)512 * 4);
    int*   csr_src = (int*)p;   p += align256((size_t)E * 4);
    __bf16* Whi    = (__bf16*)p; p += align256((size_t)8192 * 2);
    __bf16* Wlo    = (__bf16*)p; p += align256((size_t)8192 * 2);

    int Ntiles = (N + 15) / 16;                  // 6250
    int NB = (N + 255) / 256;                    // 391 (must be <= 512)

    pack_w<<<32, 256, 0, stream>>>(W, Whi, Wlo);
    hipMemsetAsync(counts, 0, (size_t)N * 4, stream);
    gemm_h<<<(Ntiles + 3) / 4, 256, 0, stream>>>(feat, Whi, Wlo, attn_l, attn_r,
                                                 h, el, er, N, Ntiles);
    count_deg<<<(E + 255) / 256, 256, 0, stream>>>(dst, counts, E);
    block_reduce<<<NB, 256, 0, stream>>>(counts, bsum, N);
    scan_bsum<<<1, 512, 0, stream>>>(bsum, NB, offsets, N);
    scan_final<<<NB, 256, 0, stream>>>(counts, bsum, offsets, cursor, N);
    fill_csr<<<(E + 255) / 256, 256, 0, stream>>>(src, dst, cursor, csr_src, E);

    aggregate<<<(N + 3) / 4, 256, 0, stream>>>(offsets, csr_src, el, er, h, bias, out, N);
}